// Round 4
// baseline (407.266 us; speedup 1.0000x reference)
//
#include <hip/hip_runtime.h>

typedef unsigned short u16;
typedef __attribute__((ext_vector_type(8))) short bf16x8;
typedef __attribute__((ext_vector_type(4))) float f32x4;

struct __align__(8) U16x4 { u16 a, b, c, d; };

__device__ __forceinline__ u16 f2bf(float f) {
  union { float f; unsigned int u; } cv; cv.f = f;
  unsigned int u = cv.u;
  unsigned int r = (u + 0x7fffu + ((u >> 16) & 1u)) >> 16;  // RNE
  return (u16)r;
}

__device__ __forceinline__ void gld16(const u16* g, u16* l) {
  __builtin_amdgcn_global_load_lds((const __attribute__((address_space(1))) void*)g,
                                   (__attribute__((address_space(3))) void*)l, 16, 0, 0);
}

// ---------------------------------------------------------------------------
// conv: fp32 x-slice [32768,256] -> bf16 xbf, same layout.
// ---------------------------------------------------------------------------
__global__ void conv_k(const float* __restrict__ x, u16* __restrict__ xbf) {
  size_t i = ((size_t)blockIdx.x * 256 + threadIdx.x) * 8;
  u16 tmp[8];
  #pragma unroll
  for (int j = 0; j < 8; j++) tmp[j] = f2bf(x[i + j]);
  *(bf16x8*)&xbf[i] = *(const bf16x8*)&tmp[0];
}

// ---------------------------------------------------------------------------
// Prep: fp32 weights -> bf16 transposed weights.
// WT1[1536][256]: rows 0-511 = Wq cols, rows 512-1535 = Wkv cols (k then v).
// WoT[256][512] = Wo^T.
// ---------------------------------------------------------------------------
__global__ void prep_k(const float* __restrict__ Wq, const float* __restrict__ Wkv,
                       const float* __restrict__ Wo, u16* __restrict__ WT1,
                       u16* __restrict__ WoT) {
  int idx = blockIdx.x * 256 + threadIdx.x;
  if (idx < 1536 * 256) {
    int c = idx >> 8, k = idx & 255;
    WT1[idx] = (c < 512) ? f2bf(Wq[(size_t)k * 512 + c])
                         : f2bf(Wkv[(size_t)k * 1024 + (c - 512)]);
  }
  if (idx < 256 * 512) {
    int nn = idx >> 9, kk = idx & 511;
    WoT[idx] = f2bf(Wo[(size_t)kk * 256 + nn]);
  }
}

// ---------------------------------------------------------------------------
// Shared GEMM core: 128x128x32 tiles, 256 threads (4 waves, 2x2 of 64x64),
// mfma_f32_16x16x32_bf16, global_load_lds width-16 staging (m97 structure).
// All kernels operate on ONE tied-batch group b~ (32768 token rows, 8 heads).
//
// KIND 1: QKV.  A=xbf [32768,256] bf16, B=WT1 [1536,256] bf16.
//         cols <1024 -> QKb flat [32768,1024]; cols >=1024 -> VTb[h][rd][j].
// KIND 2: dots. A=Q (QKb cols 0-511), B=K (QKb cols 512-1023), tied-(r,d)
//         gather via per-kb base; out fp32 SPb[s][h][i][j]. split-K.
// KIND 3: PV.   A=Pb[h][i][j], B=VTb[h][rd][j]; out OTb[h][i][rd] bf16.
// KIND 4: proj. A=OTb gathered per (h,d) k-block, B=WoT; out fp32 rows + bo.
// ---------------------------------------------------------------------------
template<int KIND>
__global__ void __launch_bounds__(256, 2) gemm_k(
    const u16* __restrict__ A, const u16* __restrict__ B,
    u16* __restrict__ C, u16* __restrict__ C2,
    float* __restrict__ SF, const float* __restrict__ bias, int nkRt) {
  __shared__ __align__(16) u16 lA[128 * 32];
  __shared__ __align__(16) u16 lB[128 * 32];

  const int tid  = threadIdx.x;
  const int bid  = blockIdx.x;
  const int lane = tid & 63;
  const int wv   = tid >> 6;
  const int l15  = lane & 15;
  const int quad = lane >> 4;
  const int mq   = (wv & 1) * 64;
  const int nq   = (wv >> 1) * 64;

  int m0, n0, NK, kb0 = 0;
  int r4 = 0, i0 = 0, s = 0, p = 0;
  if constexpr (KIND == 1) {
    m0 = (bid % 256) * 128; n0 = (bid / 256) * 128; NK = 8;
  } else if constexpr (KIND == 2) {
    n0 = (bid & 3) * 128; m0 = ((bid >> 2) & 3) * 128;
    p = (bid >> 4) & 7; s = bid >> 7; NK = nkRt; kb0 = s * nkRt;
  } else if constexpr (KIND == 3) {
    n0 = (bid & 31) * 128; m0 = ((bid >> 5) & 3) * 128; p = bid >> 7; NK = 16;
  } else {
    n0 = (bid & 1) * 128; m0 = (bid >> 1) * 128; NK = 16;
    r4 = (m0 >> 9) & 63; i0 = m0 & 511;
  }

  f32x4 acc[4][4];
  #pragma unroll
  for (int i = 0; i < 4; i++)
    #pragma unroll
    for (int j = 0; j < 4; j++)
      #pragma unroll
      for (int g = 0; g < 4; g++) acc[i][j][g] = 0.f;

  const int ar0 = tid >> 2;       // staging row (0..63); +64 for second chunk
  const int ac0 = (tid & 3) * 8;  // staging col (elems)

  for (int t = 0; t < NK; t++) {
    const int kb = kb0 + t;
    size_t aBase, bBase; int aRS, bRS;
    if constexpr (KIND == 1) {
      aBase = (size_t)m0 * 256 + kb * 32; aRS = 256;
      bBase = (size_t)n0 * 256 + kb * 32; bRS = 256;
    } else if constexpr (KIND == 2) {
      int r = kb >> 1, dlo = (kb & 1) * 32;
      size_t rowblk = (size_t)r * 512;
      aBase = (rowblk + m0) * 1024 + p * 64 + dlo;        aRS = 1024;
      bBase = (rowblk + n0) * 1024 + 512 + p * 64 + dlo;  bRS = 1024;
    } else if constexpr (KIND == 3) {
      aBase = ((size_t)p * 512 + m0) * 512 + kb * 32;   aRS = 512;
      bBase = ((size_t)p * 4096 + n0) * 512 + kb * 32;  bRS = 512;
    } else {
      int h = kb >> 1, dlo = (kb & 1) * 32;
      aBase = ((size_t)h * 512 + i0) * 4096 + r4 * 64 + dlo; aRS = 4096;
      bBase = (size_t)n0 * 512 + kb * 32; bRS = 512;
    }
    gld16(A + aBase + (size_t)ar0 * aRS + ac0,        &lA[tid * 8]);
    gld16(A + aBase + (size_t)(ar0 + 64) * aRS + ac0, &lA[(tid + 256) * 8]);
    gld16(B + bBase + (size_t)ar0 * bRS + ac0,        &lB[tid * 8]);
    gld16(B + bBase + (size_t)(ar0 + 64) * bRS + ac0, &lB[(tid + 256) * 8]);
    __syncthreads();

    bf16x8 af[4], bfr[4];
    #pragma unroll
    for (int mi = 0; mi < 4; mi++)
      af[mi] = *(const bf16x8*)&lA[(mq + mi * 16 + l15) * 32 + quad * 8];
    #pragma unroll
    for (int ni = 0; ni < 4; ni++)
      bfr[ni] = *(const bf16x8*)&lB[(nq + ni * 16 + l15) * 32 + quad * 8];
    #pragma unroll
    for (int mi = 0; mi < 4; mi++)
      #pragma unroll
      for (int ni = 0; ni < 4; ni++)
        acc[mi][ni] = __builtin_amdgcn_mfma_f32_16x16x32_bf16(af[mi], bfr[ni], acc[mi][ni], 0, 0, 0);
    __syncthreads();
  }

  // Epilogue. C/D frag: col = lane&15, row = quad*4 + reg (verified m89/m91).
  #pragma unroll
  for (int mi = 0; mi < 4; mi++) {
    #pragma unroll
    for (int ni = 0; ni < 4; ni++) {
      if constexpr (KIND == 1) {
        int cgl = n0 + nq + ni * 16 + l15;
        if (n0 < 1024) {
          #pragma unroll
          for (int g = 0; g < 4; g++) {
            int m = m0 + mq + mi * 16 + quad * 4 + g;
            C[(size_t)m * 1024 + cgl] = f2bf(acc[mi][ni][g]);
          }
        } else {
          int cc = cgl - 1024; int h = cc >> 6, d = cc & 63;
          int r = (m0 >> 9) & 63;
          int j0 = (m0 & 511) + mq + mi * 16 + quad * 4;
          U16x4 pk;
          pk.a = f2bf(acc[mi][ni][0]); pk.b = f2bf(acc[mi][ni][1]);
          pk.c = f2bf(acc[mi][ni][2]); pk.d = f2bf(acc[mi][ni][3]);
          *(U16x4*)&C2[((size_t)h * 4096 + r * 64 + d) * 512 + j0] = pk;
        }
      } else if constexpr (KIND == 2) {
        int gn = n0 + nq + ni * 16 + l15;
        #pragma unroll
        for (int g = 0; g < 4; g++) {
          int gm = m0 + mq + mi * 16 + quad * 4 + g;
          SF[((size_t)(s * 8 + p) * 512 + gm) * 512 + gn] = acc[mi][ni][g];
        }
      } else if constexpr (KIND == 3) {
        int gn = n0 + nq + ni * 16 + l15;
        #pragma unroll
        for (int g = 0; g < 4; g++) {
          int gm = m0 + mq + mi * 16 + quad * 4 + g;
          C[((size_t)p * 512 + gm) * 4096 + gn] = f2bf(acc[mi][ni][g]);
        }
      } else {
        int gn = n0 + nq + ni * 16 + l15;
        float bo_f = bias[gn];
        #pragma unroll
        for (int g = 0; g < 4; g++) {
          int gm = m0 + mq + mi * 16 + quad * 4 + g;
          SF[(size_t)gm * 256 + gn] = acc[mi][ni][g] + bo_f;   // fp32 output
        }
      }
    }
  }
}

// ---------------------------------------------------------------------------
// Softmax over j, fp32: sums split-K partials, applies scale = dh^-.5 * r^-.5
// = 1/64, emits bf16 P. One 256-thread block per (head, i) row. 8 heads.
// ---------------------------------------------------------------------------
__global__ void softmax_k(const float* __restrict__ SP, u16* __restrict__ P, int nsplit) {
  int bid = blockIdx.x;
  int p = bid >> 9, i = bid & 511;
  int t = threadIdx.x;
  size_t rowbase = ((size_t)p * 512 + i) * 512;
  float v0 = 0.f, v1 = 0.f;
  for (int ss = 0; ss < nsplit; ss++) {
    size_t off = (size_t)ss * 8 * 512 * 512;
    v0 += SP[off + rowbase + t];
    v1 += SP[off + rowbase + t + 256];
  }
  const float scale = 1.0f / 64.0f;
  v0 *= scale; v1 *= scale;

  int wv = t >> 6, ln = t & 63;
  float m = fmaxf(v0, v1);
  for (int o = 32; o > 0; o >>= 1) m = fmaxf(m, __shfl_down(m, o));
  __shared__ float sred[4];
  if (ln == 0) sred[wv] = m;
  __syncthreads();
  m = fmaxf(fmaxf(sred[0], sred[1]), fmaxf(sred[2], sred[3]));

  float e0 = expf(v0 - m), e1 = expf(v1 - m);
  float sum = e0 + e1;
  for (int o = 32; o > 0; o >>= 1) sum += __shfl_down(sum, o);
  __shared__ float sred2[4];
  if (ln == 0) sred2[wv] = sum;
  __syncthreads();
  float inv = 1.0f / (sred2[0] + sred2[1] + sred2[2] + sred2[3]);

  P[rowbase + t]       = f2bf(e0 * inv);
  P[rowbase + t + 256] = f2bf(e1 * inv);
}

// ---------------------------------------------------------------------------
// B=128, n=512, dim=256, h=8, dh=64, r=64, b~=2. fp32 in / fp32 out.
// Processed per b~; internal bf16. xbf aliases the SP split-K region
// (disjoint lifetimes: conv/G1 use xbf before G2 writes SP).
// Footprint: WT 1MB | QKb/OTb 64MB | VTb 32MB | Pb 4MB | XS max(17,ns*8)MB
// = ~133MB at ns=4 (same as round 2/3, which ran without fault).
// ---------------------------------------------------------------------------
extern "C" void kernel_launch(void* const* d_in, const int* in_sizes, int n_in,
                              void* d_out, int out_size, void* d_ws, size_t ws_size,
                              hipStream_t stream) {
  (void)in_sizes; (void)n_in; (void)out_size;
  const float* x   = (const float*)d_in[0];
  const float* Wq  = (const float*)d_in[1];
  const float* Wkv = (const float*)d_in[2];
  const float* Wo  = (const float*)d_in[3];
  const float* bo  = (const float*)d_in[4];
  float* out = (float*)d_out;

  char* ws = (char*)d_ws;
  size_t off = 0;
  u16* WT1 = (u16*)(ws + off); off += (size_t)1536 * 256 * 2;      //  768 KB
  u16* WoT = (u16*)(ws + off); off += (size_t)256 * 512 * 2;       //  256 KB
  u16* QKb = (u16*)(ws + off); off += (size_t)32768 * 1024 * 2;    //   64 MB
  u16* OTb = QKb;  // alias: OT [8][512][4096] reuses dead QK space
  u16* VTb = (u16*)(ws + off); off += (size_t)8 * 4096 * 512 * 2;  //   32 MB
  u16* Pb  = (u16*)(ws + off); off += (size_t)8 * 512 * 512 * 2;   //    4 MB
  char* XS = ws + off;                       // xbf (16.75MB) / SPb (ns*8MB)
  u16* xbf = (u16*)XS;
  float* SPb = (float*)XS;
  size_t rem = (ws_size > off) ? (ws_size - off) : 0;
  int nsplit = 4;
  while (nsplit > 1 && (size_t)nsplit * 8 * 512 * 512 * 4 > rem) nsplit >>= 1;

  prep_k<<<dim3(1536), dim3(256), 0, stream>>>(Wq, Wkv, Wo, WT1, WoT);

  for (int bt = 0; bt < 2; bt++) {
    const float* xb = x + (size_t)bt * 32768 * 256;
    float* outb = out + (size_t)bt * 32768 * 256;
    // cast x-slice to bf16 (xbf region; dead before G2 reuses it as SPb)
    conv_k<<<dim3(4096), dim3(256), 0, stream>>>(xb, xbf);
    // G1: QKV gemm [32768,256]x[256,1536] -> QKb + VTb
    gemm_k<1><<<dim3(3072), dim3(256), 0, stream>>>(xbf, WT1, QKb, VTb, nullptr, nullptr, 0);
    // G2: dots (tied r,d contraction), split-K -> SPb fp32
    gemm_k<2><<<dim3(nsplit * 128), dim3(256), 0, stream>>>(QKb, QKb, nullptr, nullptr,
                                                            SPb, nullptr, 128 / nsplit);
    // softmax rows -> Pb bf16
    softmax_k<<<dim3(4096), dim3(256), 0, stream>>>(SPb, Pb, nsplit);
    // G3: PV -> OTb (aliases QKb)
    gemm_k<3><<<dim3(1024), dim3(256), 0, stream>>>(Pb, VTb, OTb, nullptr, nullptr, nullptr, 0);
    // G4: output projection + bias -> fp32 out
    gemm_k<4><<<dim3(512), dim3(256), 0, stream>>>(OTb, WoT, nullptr, nullptr, outb, bo, 0);
  }
}